// Round 2
// baseline (29230.685 us; speedup 1.0000x reference)
//
#include <hip/hip_runtime.h>

#define Bsz 1024
#define Tn  256
#define Fn  128
#define Hn  16

typedef float v4f __attribute__((ext_vector_type(4)));

// ---------- fast activations (branch-free, saturating) ----------
__device__ __forceinline__ float frcp(float x) { return __builtin_amdgcn_rcpf(x); }
__device__ __forceinline__ float sigm(float x) { return frcp(1.0f + __expf(-x)); }
__device__ __forceinline__ float tanh_fast(float x) {
    // tanh(x) = 1 - 2/(exp(2x)+1); exp->inf/0 saturates correctly
    return 1.0f - 2.0f * frcp(__expf(2.0f * x) + 1.0f);
}

// ---------- kernel 1: transpose x (B,T,F) -> xt (T,F,B) ----------
__global__ __launch_bounds__(256) void transpose_x(const float* __restrict__ x,
                                                   float* __restrict__ xt) {
    __shared__ float tile[32][33];
    const int t  = blockIdx.z;
    const int bb = blockIdx.x * 32;
    const int ff = blockIdx.y * 32;
    const int tx = threadIdx.x;   // 0..31
    const int ty = threadIdx.y;   // 0..7
#pragma unroll
    for (int i = 0; i < 4; ++i) {
        int brow = ty + i * 8;
        tile[brow][tx] = x[((size_t)(bb + brow) * Tn + t) * Fn + (ff + tx)];
    }
    __syncthreads();
#pragma unroll
    for (int i = 0; i < 4; ++i) {
        int frow = ty + i * 8;
        xt[((size_t)t * Fn + (ff + frow)) * Bsz + (bb + tx)] = tile[tx][frow];
    }
}

// ---------- kernel 2: the recurrent LSTM ----------
// block: 256 threads = 256 batch elems, one feature per blockIdx.x.
// Weights staged in LDS ONCE (transposed to [k][j] for contiguous float4
// reads), gates accumulated in float4 regs -> v_pk_fma_f32 packed math.
__global__ __launch_bounds__(256, 2) void lstm_fwd(const float* __restrict__ xt,
                                                   const float* __restrict__ Wih,   // (F,64)
                                                   const float* __restrict__ Whh,   // (F,64,16)
                                                   const float* __restrict__ bih,   // (F,64)
                                                   const float* __restrict__ bhh,   // (F,64)
                                                   const float* __restrict__ init_h,
                                                   const float* __restrict__ init_c,
                                                   float* __restrict__ hout) {      // (F*16, B)
    const int f   = blockIdx.x;
    const int b   = blockIdx.y * 256 + threadIdx.x;
    const int tid = threadIdx.x;

    __shared__ float sWt[16 * 64];   // sWt[k*64 + j] = Whh[f][j][k]  (4 KB)
    __shared__ float sWx[64];
    __shared__ float sBs[64];

    const float* __restrict__ W = Whh + (size_t)f * 64 * 16;
#pragma unroll
    for (int e = 0; e < 4; ++e) {
        int idx = tid + e * 256;          // 0..1023
        int j = idx & 63, k = idx >> 6;
        sWt[k * 64 + j] = W[j * 16 + k];
    }
    if (tid < 64) {
        sWx[tid] = Wih[f * 64 + tid];
        sBs[tid] = bih[f * 64 + tid] + bhh[f * 64 + tid];
    }
    __syncthreads();

    float h[16], c[16];
#pragma unroll
    for (int j = 0; j < 16; ++j) {
        h[j] = init_h[f * 16 + j];
        c[j] = init_c[f * 16 + j];
    }

    const float* __restrict__ xp = xt + (size_t)f * Bsz + b;
    float xv = xp[0];

    for (int t = 0; t < Tn; ++t) {
        // prefetch next timestep's x while we compute this one
        const float xv_next = (t + 1 < Tn) ? xp[(size_t)(t + 1) * Fn * Bsz] : 0.0f;

        const v4f* __restrict__ wx4 = (const v4f*)sWx;
        const v4f* __restrict__ bs4 = (const v4f*)sBs;
        v4f g[16];                       // all 64 gate pre-activations
#pragma unroll
        for (int q = 0; q < 16; ++q) g[q] = bs4[q] + wx4[q] * xv;

#pragma unroll
        for (int k = 0; k < 16; ++k) {
            const float hk = h[k];
            const v4f* __restrict__ wt = (const v4f*)(sWt + k * 64);
#pragma unroll
            for (int q = 0; q < 16; ++q) g[q] += wt[q] * hk;   // v_pk_fma_f32 x2
        }

#pragma unroll
        for (int j = 0; j < 16; ++j) {
            const float gi = g[(j >> 2)][j & 3];
            const float gf = g[4 + (j >> 2)][j & 3];
            const float gg = g[8 + (j >> 2)][j & 3];
            const float go = g[12 + (j >> 2)][j & 3];
            const float cj = __fmaf_rn(sigm(gf), c[j], sigm(gi) * tanh_fast(gg));
            c[j] = cj;
            h[j] = sigm(go) * tanh_fast(cj);
        }
        xv = xv_next;
    }

#pragma unroll
    for (int j = 0; j < 16; ++j)
        hout[(size_t)(f * 16 + j) * Bsz + b] = h[j];
}

// ---------- kernel 3: out[b] = b_fuse + sum_k hout[k][b]*W_fuse[k] ----------
// split-k: 256 threads = 64 batches x 4 k-quarters, LDS reduce.
__global__ __launch_bounds__(256) void fuse_out(const float* __restrict__ hout,
                                                const float* __restrict__ Wf,
                                                const float* __restrict__ bf,
                                                float* __restrict__ out) {
    __shared__ float part[4][64];
    const int bl = threadIdx.x & 63;
    const int q  = threadIdx.x >> 6;
    const int b  = blockIdx.x * 64 + bl;
    float acc = 0.0f;
#pragma unroll 8
    for (int i = 0; i < 512; ++i) {
        const int k = q * 512 + i;
        acc = __fmaf_rn(hout[(size_t)k * Bsz + b], Wf[k], acc);
    }
    part[q][bl] = acc;
    __syncthreads();
    if (q == 0)
        out[b] = part[0][bl] + part[1][bl] + part[2][bl] + part[3][bl] + bf[0];
}

extern "C" void kernel_launch(void* const* d_in, const int* in_sizes, int n_in,
                              void* d_out, int out_size, void* d_ws, size_t ws_size,
                              hipStream_t stream) {
    const float* x      = (const float*)d_in[0];
    const float* Wih    = (const float*)d_in[1];
    const float* Whh    = (const float*)d_in[2];
    const float* bih    = (const float*)d_in[3];
    const float* bhh    = (const float*)d_in[4];
    const float* init_h = (const float*)d_in[5];
    const float* init_c = (const float*)d_in[6];
    const float* Wf     = (const float*)d_in[7];
    const float* bf     = (const float*)d_in[8];
    float* out = (float*)d_out;

    char* ws = (char*)d_ws;
    float* xt   = (float*)ws;                         // 134,217,728 B  (T,F,B)
    float* hout = (float*)(ws + (size_t)134217728);   // 8,388,608 B   (F*16, B)

    transpose_x<<<dim3(32, 4, 256), dim3(32, 8), 0, stream>>>(x, xt);
    lstm_fwd<<<dim3(Fn, Bsz / 256), 256, 0, stream>>>(xt, Wih, Whh, bih, bhh,
                                                      init_h, init_c, hout);
    fuse_out<<<Bsz / 64, 256, 0, stream>>>(hout, Wf, bf, out);
}

// Round 3
// 1217.129 us; speedup vs baseline: 24.0161x; 24.0161x over previous
//
#include <hip/hip_runtime.h>

#define Bsz 1024
#define Tn  256
#define Fn  128
#define Hn  16

typedef float v2f __attribute__((ext_vector_type(2)));

// ---------- fast activations (branch-free, saturating) ----------
__device__ __forceinline__ float frcp(float x) { return __builtin_amdgcn_rcpf(x); }
__device__ __forceinline__ float sigm(float x) { return frcp(1.0f + __expf(-x)); }
__device__ __forceinline__ float tanh_fast(float x) {
    // tanh(x) = 1 - 2/(exp(2x)+1); exp->inf/0 saturates correctly
    return 1.0f - 2.0f * frcp(__expf(2.0f * x) + 1.0f);
}

// ---------- kernel 1: the recurrent LSTM ----------
// Lane owns one (b, f, j): h[j], c[j], and gate rows {j,16+j,32+j,48+j} of
// W_hh in registers (packed float2 -> v_pk_fma_f32). 16 lanes = one LSTM
// cell; 4 cells/wave; block = one b x 16 f. h broadcast via static
// ds_swizzle within the 16-lane group. No LDS, no in-loop memory but x.
__global__ __launch_bounds__(256) void lstm_fwd(const float* __restrict__ x,     // (B,T,F)
                                                const float* __restrict__ Wih,   // (F,64)
                                                const float* __restrict__ Whh,   // (F,64,16)
                                                const float* __restrict__ bih,   // (F,64)
                                                const float* __restrict__ bhh,   // (F,64)
                                                const float* __restrict__ init_h,
                                                const float* __restrict__ init_c,
                                                float* __restrict__ hout) {      // (B, F*16)
    const int tid  = threadIdx.x;
    const int lane = tid & 63;
    const int wv   = tid >> 6;            // wave in block: 0..3
    const int j    = lane & 15;           // hidden index this lane owns
    const int fsub = (lane >> 4) & 3;     // cell within wave: 0..3
    const int b    = blockIdx.x >> 3;
    const int fc   = blockIdx.x & 7;
    const int f    = fc * 16 + wv * 4 + fsub;

    // ---- register-resident weights, packed (i,f) and (g,o) pairs ----
    const float* __restrict__ Wr = Whh + (size_t)f * 64 * 16;
    v2f wif[16], wgo[16];
#pragma unroll
    for (int q = 0; q < 4; ++q) {
        const float4 ri = *(const float4*)(Wr + (j     ) * 16 + q * 4);
        const float4 rf = *(const float4*)(Wr + (16 + j) * 16 + q * 4);
        const float4 rg = *(const float4*)(Wr + (32 + j) * 16 + q * 4);
        const float4 ro = *(const float4*)(Wr + (48 + j) * 16 + q * 4);
        wif[q * 4 + 0] = v2f{ri.x, rf.x};  wgo[q * 4 + 0] = v2f{rg.x, ro.x};
        wif[q * 4 + 1] = v2f{ri.y, rf.y};  wgo[q * 4 + 1] = v2f{rg.y, ro.y};
        wif[q * 4 + 2] = v2f{ri.z, rf.z};  wgo[q * 4 + 2] = v2f{rg.z, ro.z};
        wif[q * 4 + 3] = v2f{ri.w, rf.w};  wgo[q * 4 + 3] = v2f{rg.w, ro.w};
    }
    const int fb = f * 64;
    const v2f bias_if = v2f{bih[fb + j]      + bhh[fb + j],
                            bih[fb + 16 + j] + bhh[fb + 16 + j]};
    const v2f bias_go = v2f{bih[fb + 32 + j] + bhh[fb + 32 + j],
                            bih[fb + 48 + j] + bhh[fb + 48 + j]};
    const v2f wx_if   = v2f{Wih[fb + j],      Wih[fb + 16 + j]};
    const v2f wx_go   = v2f{Wih[fb + 32 + j], Wih[fb + 48 + j]};

    float h_own = init_h[f * 16 + j];
    float c_own = init_c[f * 16 + j];

    const float* __restrict__ xp = x + (size_t)b * Tn * Fn + f;
    float xv = xp[0];

    for (int t = 0; t < Tn; ++t) {
        const float xnext = xp[(t + 1 < Tn ? t + 1 : t) * Fn];   // prefetch

        v2f aif = bias_if + wx_if * v2f{xv, xv};
        v2f ago = bias_go + wx_go * v2f{xv, xv};

        // broadcast h[k] from lane (group|k); imm = (k<<5)|0x10 (BitMode:
        // src = (lane & 0x10) | k per 32-lane half)
#define STEPK(K)                                                              \
        {                                                                     \
            const int hi_ = __builtin_amdgcn_ds_swizzle(                      \
                __float_as_int(h_own), ((K) << 5) | 0x10);                    \
            const float hk = __int_as_float(hi_);                            \
            const v2f h2 = v2f{hk, hk};                                       \
            aif += wif[K] * h2;                                               \
            ago += wgo[K] * h2;                                               \
        }
        STEPK(0)  STEPK(1)  STEPK(2)  STEPK(3)
        STEPK(4)  STEPK(5)  STEPK(6)  STEPK(7)
        STEPK(8)  STEPK(9)  STEPK(10) STEPK(11)
        STEPK(12) STEPK(13) STEPK(14) STEPK(15)
#undef STEPK

        const float ig = sigm(aif.x);
        const float fg = sigm(aif.y);
        const float gv = tanh_fast(ago.x);
        const float og = sigm(ago.y);
        c_own = __fmaf_rn(fg, c_own, ig * gv);
        h_own = og * tanh_fast(c_own);
        xv = xnext;
    }

    // (b, f*16+j); within a wave this is 64 consecutive floats -> coalesced
    hout[(size_t)b * (Fn * Hn) + f * Hn + j] = h_own;
}

// ---------- kernel 2: out[b] = b_fuse + sum_k hout[b][k]*W_fuse[k] ----------
__global__ __launch_bounds__(256) void fuse_out(const float* __restrict__ hout,
                                                const float* __restrict__ Wf,
                                                const float* __restrict__ bf,
                                                float* __restrict__ out) {
    __shared__ float part[4];
    const int b = blockIdx.x, tid = threadIdx.x;
    float acc = 0.0f;
#pragma unroll
    for (int q = 0; q < 8; ++q) {
        const int k = q * 256 + tid;
        acc = __fmaf_rn(hout[(size_t)b * (Fn * Hn) + k], Wf[k], acc);
    }
#pragma unroll
    for (int off = 32; off; off >>= 1) acc += __shfl_down(acc, off, 64);
    if ((tid & 63) == 0) part[tid >> 6] = acc;
    __syncthreads();
    if (tid == 0) out[b] = part[0] + part[1] + part[2] + part[3] + bf[0];
}

extern "C" void kernel_launch(void* const* d_in, const int* in_sizes, int n_in,
                              void* d_out, int out_size, void* d_ws, size_t ws_size,
                              hipStream_t stream) {
    const float* x      = (const float*)d_in[0];
    const float* Wih    = (const float*)d_in[1];
    const float* Whh    = (const float*)d_in[2];
    const float* bih    = (const float*)d_in[3];
    const float* bhh    = (const float*)d_in[4];
    const float* init_h = (const float*)d_in[5];
    const float* init_c = (const float*)d_in[6];
    const float* Wf     = (const float*)d_in[7];
    const float* bf     = (const float*)d_in[8];
    float* out = (float*)d_out;

    float* hout = (float*)d_ws;   // (B, F*16) = 8,388,608 B

    lstm_fwd<<<Bsz * 8, 256, 0, stream>>>(x, Wih, Whh, bih, bhh,
                                          init_h, init_c, hout);
    fuse_out<<<Bsz, 256, 0, stream>>>(hout, Wf, bf, out);
}

// Round 4
// 1141.428 us; speedup vs baseline: 25.6089x; 1.0663x over previous
//
#include <hip/hip_runtime.h>

#define Bsz 1024
#define Tn  256
#define Fn  128
#define Hn  16

typedef float v2f __attribute__((ext_vector_type(2)));
typedef float v4f __attribute__((ext_vector_type(4)));

__device__ __forceinline__ float frcp(float x)  { return __builtin_amdgcn_rcpf(x); }
__device__ __forceinline__ float fexp2(float x) { return __builtin_amdgcn_exp2f(x); }

#define LOG2E  1.44269504088896f
#define L2E2   2.88539008177793f   // 2*log2(e)

// ---------- kernel 1: the recurrent LSTM ----------
// Lane owns one (b, f, j). Weights register-resident as (k,k+1) v2f pairs,
// pre-scaled into exp2 domain (sign folded). h exchanged through LDS:
// 1 ds_write_b32 + 4 broadcast ds_read_b128 per step (vs 16 ds_swizzle).
// Gates accumulate as v2f k-pairs -> v_pk_fma_f32 with NO splat movs.
__global__ __launch_bounds__(256, 4) void lstm_fwd(const float* __restrict__ x,     // (B,T,F)
                                                   const float* __restrict__ Wih,   // (F,64)
                                                   const float* __restrict__ Whh,   // (F,64,16)
                                                   const float* __restrict__ bih,   // (F,64)
                                                   const float* __restrict__ bhh,   // (F,64)
                                                   const float* __restrict__ init_h,
                                                   const float* __restrict__ init_c,
                                                   float* __restrict__ hout) {      // (B, F*16)
    const int tid  = threadIdx.x;
    const int lane = tid & 63;
    const int wv   = tid >> 6;            // wave in block: 0..3
    const int j    = lane & 15;           // hidden index this lane owns
    const int fsub = (lane >> 4) & 3;     // cell within wave: 0..3
    const int b    = blockIdx.x >> 3;
    const int fc   = blockIdx.x & 7;
    const int f    = fc * 16 + wv * 4 + fsub;

    // ---- register-resident scaled weights: 8 k-pairs per gate ----
    const float* __restrict__ Wr = Whh + (size_t)f * 64 * 16;
    v2f wi[8], wf[8], wg[8], wo[8];
#pragma unroll
    for (int q = 0; q < 8; ++q) {
        wi[q] = v2f{Wr[(j)      * 16 + 2 * q], Wr[(j)      * 16 + 2 * q + 1]} * (-LOG2E);
        wf[q] = v2f{Wr[(16 + j) * 16 + 2 * q], Wr[(16 + j) * 16 + 2 * q + 1]} * (-LOG2E);
        wg[q] = v2f{Wr[(32 + j) * 16 + 2 * q], Wr[(32 + j) * 16 + 2 * q + 1]} * ( L2E2);
        wo[q] = v2f{Wr[(48 + j) * 16 + 2 * q], Wr[(48 + j) * 16 + 2 * q + 1]} * (-LOG2E);
    }
    const int fb = f * 64;
    const float bi = (bih[fb + j]      + bhh[fb + j])      * (-LOG2E);
    const float bf_ = (bih[fb + 16 + j] + bhh[fb + 16 + j]) * (-LOG2E);
    const float bg = (bih[fb + 32 + j] + bhh[fb + 32 + j]) * ( L2E2);
    const float bo = (bih[fb + 48 + j] + bhh[fb + 48 + j]) * (-LOG2E);
    const float wxi = Wih[fb + j]      * (-LOG2E);
    const float wxf = Wih[fb + 16 + j] * (-LOG2E);
    const float wxg = Wih[fb + 32 + j] * ( L2E2);
    const float wxo = Wih[fb + 48 + j] * (-LOG2E);

    float h_own = init_h[f * 16 + j];
    float c_own = init_c[f * 16 + j];

    __shared__ float sh[4][4][16];        // [wave][cell][j], 1 KB
    float* __restrict__ shp = &sh[wv][fsub][0];

    const float* __restrict__ xp = x + (size_t)b * Tn * Fn + f;
    float xv = xp[0];

    for (int t = 0; t < Tn; ++t) {
        // prefetch next x early (uniform select keeps t=255 in-bounds)
        const float xnext = xp[(t + 1 < Tn) ? Fn : 0];
        xp += Fn;

        shp[j] = h_own;                   // ds_write_b32
        asm volatile("" ::: "memory");    // no stale-LDS caching across lanes
        const v4f h03  = *(const v4f*)(shp);       // broadcast ds_read_b128
        const v4f h47  = *(const v4f*)(shp + 4);
        const v4f h8b  = *(const v4f*)(shp + 8);
        const v4f hcf  = *(const v4f*)(shp + 12);
        const v2f p0 = __builtin_shufflevector(h03, h03, 0, 1);
        const v2f p1 = __builtin_shufflevector(h03, h03, 2, 3);
        const v2f p2 = __builtin_shufflevector(h47, h47, 0, 1);
        const v2f p3 = __builtin_shufflevector(h47, h47, 2, 3);
        const v2f p4 = __builtin_shufflevector(h8b, h8b, 0, 1);
        const v2f p5 = __builtin_shufflevector(h8b, h8b, 2, 3);
        const v2f p6 = __builtin_shufflevector(hcf, hcf, 0, 1);
        const v2f p7 = __builtin_shufflevector(hcf, hcf, 2, 3);

        v2f ai = wi[0] * p0, af = wf[0] * p0, ag = wg[0] * p0, ao = wo[0] * p0;
#define ACC(Q) ai += wi[Q] * p##Q; af += wf[Q] * p##Q; ag += wg[Q] * p##Q; ao += wo[Q] * p##Q;
        ACC(1) ACC(2) ACC(3) ACC(4) ACC(5) ACC(6) ACC(7)
#undef ACC
        const float gi = ai.x + ai.y + __fmaf_rn(wxi, xv, bi);
        const float gf = af.x + af.y + __fmaf_rn(wxf, xv, bf_);
        const float gg = ag.x + ag.y + __fmaf_rn(wxg, xv, bg);
        const float go = ao.x + ao.y + __fmaf_rn(wxo, xv, bo);

        // exp2-domain activations, shared reciprocals
        const float Ei = fexp2(gi);
        const float Ef = fexp2(gf);
        const float Eg = fexp2(gg);
        const float Eo = fexp2(go);
        const float Rf  = frcp(1.0f + Ef);                    // = sigmoid(f)
        const float Rig = frcp((1.0f + Ei) * (1.0f + Eg));
        c_own = __fmaf_rn(c_own, Rf, (Eg - 1.0f) * Rig);      // f*c + i*tanh(g)
        const float cs = fminf(c_own * L2E2, 80.0f);          // clamp kills inf*0
        const float Ec = fexp2(cs);
        const float Roc = frcp((1.0f + Eo) * (1.0f + Ec));
        h_own = (Ec - 1.0f) * Roc;                            // o*tanh(c)

        xv = xnext;
    }

    hout[(size_t)b * (Fn * Hn) + f * Hn + j] = h_own;
}

// ---------- kernel 2: out[b] = b_fuse + sum_k hout[b][k]*W_fuse[k] ----------
__global__ __launch_bounds__(256) void fuse_out(const float* __restrict__ hout,
                                                const float* __restrict__ Wf,
                                                const float* __restrict__ bfu,
                                                float* __restrict__ out) {
    __shared__ float part[4];
    const int b = blockIdx.x, tid = threadIdx.x;
    float acc = 0.0f;
#pragma unroll
    for (int q = 0; q < 8; ++q) {
        const int k = q * 256 + tid;
        acc = __fmaf_rn(hout[(size_t)b * (Fn * Hn) + k], Wf[k], acc);
    }
#pragma unroll
    for (int off = 32; off; off >>= 1) acc += __shfl_down(acc, off, 64);
    if ((tid & 63) == 0) part[tid >> 6] = acc;
    __syncthreads();
    if (tid == 0) out[b] = part[0] + part[1] + part[2] + part[3] + bfu[0];
}

extern "C" void kernel_launch(void* const* d_in, const int* in_sizes, int n_in,
                              void* d_out, int out_size, void* d_ws, size_t ws_size,
                              hipStream_t stream) {
    const float* x      = (const float*)d_in[0];
    const float* Wih    = (const float*)d_in[1];
    const float* Whh    = (const float*)d_in[2];
    const float* bih    = (const float*)d_in[3];
    const float* bhh    = (const float*)d_in[4];
    const float* init_h = (const float*)d_in[5];
    const float* init_c = (const float*)d_in[6];
    const float* Wf     = (const float*)d_in[7];
    const float* bf     = (const float*)d_in[8];
    float* out = (float*)d_out;

    float* hout = (float*)d_ws;   // (B, F*16) = 8,388,608 B

    lstm_fwd<<<Bsz * 8, 256, 0, stream>>>(x, Wih, Whh, bih, bhh,
                                          init_h, init_c, hout);
    fuse_out<<<Bsz, 256, 0, stream>>>(hout, Wf, bf, out);
}

// Round 7
// 840.147 us; speedup vs baseline: 34.7924x; 1.3586x over previous
//
#include <hip/hip_runtime.h>

#define Bsz 1024
#define Tn  256
#define Fn  128

typedef float f32x4 __attribute__((ext_vector_type(4)));
typedef short s16x8 __attribute__((ext_vector_type(8)));

#define LOG2E 1.44269504088896f
#define L2E2  2.88539008177793f

__device__ __forceinline__ float frcp(float x)  { return __builtin_amdgcn_rcpf(x); }
__device__ __forceinline__ float fexp2(float x) { return __builtin_amdgcn_exp2f(x); }
__device__ __forceinline__ unsigned bf16bits(float v) {   // RNE f32 -> bf16 bits
    unsigned x = __float_as_uint(v);
    return (x + 0x7FFFu + ((x >> 16) & 1u)) >> 16;
}
__device__ __forceinline__ float fromhi(unsigned hb) { return __uint_as_float(hb << 16); }

union FragU { unsigned u[4]; s16x8 v; };

// ---------- kernel 1: transpose x (B,T,F) -> xt (T,F,B), plain f32 ----------
__global__ __launch_bounds__(256) void transpose_x(const float* __restrict__ x,
                                                   float* __restrict__ xt) {
    __shared__ float tile[32][33];
    const int t  = blockIdx.z;
    const int bb = blockIdx.x * 32;
    const int ff = blockIdx.y * 32;
    const int tx = threadIdx.x;   // 0..31
    const int ty = threadIdx.y;   // 0..7
#pragma unroll
    for (int i = 0; i < 4; ++i) {
        int brow = ty + i * 8;
        tile[brow][tx] = x[((size_t)(bb + brow) * Tn + t) * Fn + (ff + tx)];
    }
    __syncthreads();
#pragma unroll
    for (int i = 0; i < 4; ++i) {
        int frow = ty + i * 8;
        xt[((size_t)t * Fn + (ff + frow)) * Bsz + (bb + tx)] = tile[tx][frow];
    }
}

// ---------- kernel 2: recurrent LSTM via MFMA (hardened) ----------
// wave = 1 feature x 16 batches. Per gate tile g (16x16):
//   acc = MFMA(A1=[W_hi|W_hi], B1=[h_hi;h_lo], MFMA(A2=[W_lo|0], B1, biasC))
// then gate = acc + wx*x on VALU. A/B share one believed lane->k map, so any
// common layout mismatch cancels exactly. ALL four gates are clamped to
// [-126,100] (v_min/v_max quiet NaN) => finite output for ANY MFMA behavior.
__global__ __launch_bounds__(256) void lstm_fwd(const float* __restrict__ xt,    // (T,F,B)
                                                const float* __restrict__ Wih,   // (F,64)
                                                const float* __restrict__ Whh,   // (F,64,16)
                                                const float* __restrict__ bih,   // (F,64)
                                                const float* __restrict__ bhh,   // (F,64)
                                                const float* __restrict__ init_h,
                                                const float* __restrict__ init_c,
                                                float* __restrict__ hout) {      // (B, F*16)
    const int tid  = threadIdx.x;
    const int wv   = tid >> 6;
    const int lane = tid & 63;
    const int gq   = lane >> 4;          // k-octet group / D-row-group
    const int col  = lane & 15;          // A: M-row; B,D: batch col
    const int f    = blockIdx.x >> 4;
    const int bc   = ((blockIdx.x & 15) << 2) | wv;
    const int bglob = bc * 16 + col;

    __shared__ unsigned sh[4][16][20];   // padded row (20 words) kills bank conflicts

    // zero-init LDS: no uninitialized read possible, ever
#pragma unroll
    for (int i = tid; i < 4 * 16 * 20; i += 256) ((unsigned*)sh)[i] = 0u;
    __syncthreads();

    // ---- persistent fragments (weights pre-scaled into exp2 domain) ----
    s16x8 A1[4], A2[4];
    f32x4 biasC[4], wxs[4];
    const int kb = (gq & 1) * 8;
#pragma unroll
    for (int g = 0; g < 4; ++g) {
        const float s = (g == 2) ? L2E2 : -LOG2E;
        const float* wrow = Whh + ((size_t)f * 64 + g * 16 + col) * 16;
        FragU a1, a2;
#pragma unroll
        for (int r = 0; r < 4; ++r) {
            float v0 = wrow[kb + 2 * r] * s, v1 = wrow[kb + 2 * r + 1] * s;
            unsigned h0 = bf16bits(v0), h1 = bf16bits(v1);
            a1.u[r] = h0 | (h1 << 16);
            if (gq < 2) {    // A2 = [W_lo | 0]: W_lo pairs with h_hi (k=0..15)
                unsigned l0 = bf16bits(v0 - fromhi(h0)), l1 = bf16bits(v1 - fromhi(h1));
                a2.u[r] = l0 | (l1 << 16);
            } else {
                a2.u[r] = 0u;
            }
        }
        A1[g] = a1.v;  A2[g] = a2.v;
        const size_t bb = (size_t)f * 64 + g * 16 + gq * 4;
        biasC[g] = f32x4{(bih[bb + 0] + bhh[bb + 0]) * s, (bih[bb + 1] + bhh[bb + 1]) * s,
                         (bih[bb + 2] + bhh[bb + 2]) * s, (bih[bb + 3] + bhh[bb + 3]) * s};
        wxs[g]   = f32x4{Wih[bb + 0] * s, Wih[bb + 1] * s, Wih[bb + 2] * s, Wih[bb + 3] * s};
    }

    f32x4 creg;
    float hq[4];
#pragma unroll
    for (int d = 0; d < 4; ++d) {
        creg[d] = init_c[f * 16 + gq * 4 + d];
        hq[d]   = init_h[f * 16 + gq * 4 + d];
    }

    unsigned* const wrHi = &sh[wv][col][2 * gq];
    const s16x8* const rdB1 = (const s16x8*)&sh[wv][col][4 * gq];

    s16x8 B1;
    // hq -> bf16 hi/lo -> LDS -> fenced b128 read (fences: rule-18 insurance)
#define REBUILD_B1()                                                            \
    {                                                                           \
        const unsigned hb0 = bf16bits(hq[0]), hb1 = bf16bits(hq[1]);            \
        const unsigned hb2 = bf16bits(hq[2]), hb3 = bf16bits(hq[3]);            \
        const float l0 = hq[0] - fromhi(hb0), l1 = hq[1] - fromhi(hb1);         \
        const float l2 = hq[2] - fromhi(hb2), l3 = hq[3] - fromhi(hb3);         \
        *(uint2*)(wrHi)     = make_uint2(hb0 | (hb1 << 16), hb2 | (hb3 << 16)); \
        *(uint2*)(wrHi + 8) = make_uint2(bf16bits(l0) | (bf16bits(l1) << 16),   \
                                         bf16bits(l2) | (bf16bits(l3) << 16));  \
        asm volatile("s_waitcnt lgkmcnt(0)" ::: "memory");                      \
        __builtin_amdgcn_sched_barrier(0);                                      \
        B1 = *rdB1;                                                             \
        asm volatile("s_waitcnt lgkmcnt(0)" ::: "memory");                      \
        __builtin_amdgcn_sched_barrier(0);                                      \
    }
    REBUILD_B1();

    const float* __restrict__ xp = xt + (size_t)f * Bsz + bglob;
    float xv = xp[0];

    for (int t = 0; t < Tn; ++t) {
        const float xnext = xp[(t + 1 < Tn) ? Fn * Bsz : 0];
        xp += Fn * Bsz;

        f32x4 acc0 = __builtin_amdgcn_mfma_f32_16x16x32_bf16(A2[0], B1, biasC[0], 0, 0, 0);
        f32x4 acc1 = __builtin_amdgcn_mfma_f32_16x16x32_bf16(A2[1], B1, biasC[1], 0, 0, 0);
        f32x4 acc2 = __builtin_amdgcn_mfma_f32_16x16x32_bf16(A2[2], B1, biasC[2], 0, 0, 0);
        f32x4 acc3 = __builtin_amdgcn_mfma_f32_16x16x32_bf16(A2[3], B1, biasC[3], 0, 0, 0);
        acc0 = __builtin_amdgcn_mfma_f32_16x16x32_bf16(A1[0], B1, acc0, 0, 0, 0);
        acc1 = __builtin_amdgcn_mfma_f32_16x16x32_bf16(A1[1], B1, acc1, 0, 0, 0);
        acc2 = __builtin_amdgcn_mfma_f32_16x16x32_bf16(A1[2], B1, acc2, 0, 0, 0);
        acc3 = __builtin_amdgcn_mfma_f32_16x16x32_bf16(A1[3], B1, acc3, 0, 0, 0);

#pragma unroll
        for (int d = 0; d < 4; ++d) {
            // gate = MFMA acc + wx*x, clamped so NaN/Inf cannot propagate
            const float gi = fmaxf(fminf(__fmaf_rn(wxs[0][d], xv, acc0[d]), 100.0f), -126.0f);
            const float gf = fmaxf(fminf(__fmaf_rn(wxs[1][d], xv, acc1[d]), 100.0f), -126.0f);
            const float gg = fmaxf(fminf(__fmaf_rn(wxs[2][d], xv, acc2[d]), 100.0f), -126.0f);
            const float go = fmaxf(fminf(__fmaf_rn(wxs[3][d], xv, acc3[d]), 100.0f), -126.0f);
            const float Ei = fexp2(gi);
            const float Ef = fexp2(gf);
            const float Eg = fexp2(gg);
            const float Eo = fexp2(go);
            const float Rf  = frcp(1.0f + Ef);
            const float Rig = frcp((1.0f + Ei) * (1.0f + Eg));
            const float cn  = __fmaf_rn(creg[d], Rf, (Eg - 1.0f) * Rig);
            creg[d] = cn;
            const float cs  = fminf(cn * L2E2, 80.0f);
            const float Ec  = fexp2(cs);
            const float Roc = frcp((1.0f + Eo) * (1.0f + Ec));
            hq[d] = (Ec - 1.0f) * Roc;
        }

        REBUILD_B1();
        xv = xnext;
    }

    *(f32x4*)(&hout[(size_t)bglob * (Fn * 16) + f * 16 + gq * 4]) =
        f32x4{hq[0], hq[1], hq[2], hq[3]};
}

// ---------- kernel 3: out[b] = b_fuse + sum_k hout[b][k]*W_fuse[k] ----------
__global__ __launch_bounds__(256) void fuse_out(const float* __restrict__ hout,
                                                const float* __restrict__ Wf,
                                                const float* __restrict__ bfu,
                                                float* __restrict__ out) {
    __shared__ float part[4];
    const int b = blockIdx.x, tid = threadIdx.x;
    float acc = 0.0f;
#pragma unroll
    for (int q = 0; q < 8; ++q) {
        const int k = q * 256 + tid;
        acc = __fmaf_rn(hout[(size_t)b * (Fn * 16) + k], Wf[k], acc);
    }
#pragma unroll
    for (int off = 32; off; off >>= 1) acc += __shfl_down(acc, off, 64);
    if ((tid & 63) == 0) part[tid >> 6] = acc;
    __syncthreads();
    if (tid == 0) out[b] = part[0] + part[1] + part[2] + part[3] + bfu[0];
}

extern "C" void kernel_launch(void* const* d_in, const int* in_sizes, int n_in,
                              void* d_out, int out_size, void* d_ws, size_t ws_size,
                              hipStream_t stream) {
    const float* x      = (const float*)d_in[0];
    const float* Wih    = (const float*)d_in[1];
    const float* Whh    = (const float*)d_in[2];
    const float* bih    = (const float*)d_in[3];
    const float* bhh    = (const float*)d_in[4];
    const float* init_h = (const float*)d_in[5];
    const float* init_c = (const float*)d_in[6];
    const float* Wf     = (const float*)d_in[7];
    const float* bf     = (const float*)d_in[8];
    float* out = (float*)d_out;

    char* ws = (char*)d_ws;
    float* xt   = (float*)ws;                          // 134,217,728 B  (T,F,B)
    float* hout = (float*)(ws + (size_t)134217728);    // 8,388,608 B   (B, F*16)

    transpose_x<<<dim3(32, 4, 256), dim3(32, 8), 0, stream>>>(x, xt);
    lstm_fwd<<<2048, 256, 0, stream>>>(xt, Wih, Whh, bih, bhh, init_h, init_c, hout);
    fuse_out<<<Bsz, 256, 0, stream>>>(hout, Wf, bf, out);
}

// Round 8
// 695.123 us; speedup vs baseline: 42.0511x; 1.2086x over previous
//
#include <hip/hip_runtime.h>

#define Bsz 1024
#define Tn  256
#define Fn  128

typedef float f32x4 __attribute__((ext_vector_type(4)));
typedef short s16x8 __attribute__((ext_vector_type(8)));

#define LOG2E 1.44269504088896f
#define L2E2  2.88539008177793f

__device__ __forceinline__ float frcp(float x)  { return __builtin_amdgcn_rcpf(x); }
__device__ __forceinline__ float fexp2(float x) { return __builtin_amdgcn_exp2f(x); }
__device__ __forceinline__ unsigned bf16bits(float v) {   // RNE f32 -> bf16 bits
    unsigned x = __float_as_uint(v);
    return (x + 0x7FFFu + ((x >> 16) & 1u)) >> 16;
}
__device__ __forceinline__ float fromhi(unsigned hb) { return __uint_as_float(hb << 16); }
__device__ __forceinline__ unsigned cvtpk(float a, float b) {  // low=bf16(a), high=bf16(b)
    unsigned r; asm("v_cvt_pk_bf16_f32 %0, %1, %2" : "=v"(r) : "v"(a), "v"(b)); return r;
}

union FragU { unsigned u[4]; s16x8 v; };

// ---------- kernel 1: transpose x (B,T,F) -> xt (T,F,B), plain f32 ----------
__global__ __launch_bounds__(256) void transpose_x(const float* __restrict__ x,
                                                   float* __restrict__ xt) {
    __shared__ float tile[32][33];
    const int t  = blockIdx.z;
    const int bb = blockIdx.x * 32;
    const int ff = blockIdx.y * 32;
    const int tx = threadIdx.x;   // 0..31
    const int ty = threadIdx.y;   // 0..7
#pragma unroll
    for (int i = 0; i < 4; ++i) {
        int brow = ty + i * 8;
        tile[brow][tx] = x[((size_t)(bb + brow) * Tn + t) * Fn + (ff + tx)];
    }
    __syncthreads();
#pragma unroll
    for (int i = 0; i < 4; ++i) {
        int frow = ty + i * 8;
        xt[((size_t)t * Fn + (ff + frow)) * Bsz + (bb + tx)] = tile[tx][frow];
    }
}

// ---------- kernel 2: recurrent LSTM via MFMA ----------
// wave = 1 feature x 16 batches. Per gate tile g (16x16):
//   acc = MFMA(A1=[W_hi|W_hi], B1=[h_hi;h_lo], MFMA(A2=[W_lo|0], B1, biasC))
// gate = acc + wx*x on VALU. NaN-safety analysis: only Eg needs the upper
// clamp (0*inf path in (Eg-1)*Rig); Ei/Ef/Eo -> inf degrade gracefully
// through rcp. cs clamp kills the tanh(c) 0*inf corner. All other clamps
// removed (measured VALU-issue-bound).
__global__ __launch_bounds__(256) void lstm_fwd(const float* __restrict__ xt,    // (T,F,B)
                                                const float* __restrict__ Wih,   // (F,64)
                                                const float* __restrict__ Whh,   // (F,64,16)
                                                const float* __restrict__ bih,   // (F,64)
                                                const float* __restrict__ bhh,   // (F,64)
                                                const float* __restrict__ init_h,
                                                const float* __restrict__ init_c,
                                                float* __restrict__ hout) {      // (B, F*16)
    const int tid  = threadIdx.x;
    const int wv   = tid >> 6;
    const int lane = tid & 63;
    const int gq   = lane >> 4;          // k-octet group / D-row-group
    const int col  = lane & 15;          // A: M-row; B,D: batch col
    const int f    = blockIdx.x >> 4;
    const int bc   = ((blockIdx.x & 15) << 2) | wv;
    const int bglob = bc * 16 + col;

    __shared__ unsigned sh[4][16][20];   // stride 20 words: 16B-aligned b128 rows

    // zero-init LDS once (no uninitialized read possible)
#pragma unroll
    for (int i = tid; i < 4 * 16 * 20; i += 256) ((unsigned*)sh)[i] = 0u;
    __syncthreads();

    // ---- persistent fragments (weights pre-scaled into exp2 domain) ----
    s16x8 A1[4], A2[4];
    f32x4 biasC[4], wxs[4];
    const int kb = (gq & 1) * 8;
#pragma unroll
    for (int g = 0; g < 4; ++g) {
        const float s = (g == 2) ? L2E2 : -LOG2E;
        const float* wrow = Whh + ((size_t)f * 64 + g * 16 + col) * 16;
        FragU a1, a2;
#pragma unroll
        for (int r = 0; r < 4; ++r) {
            float v0 = wrow[kb + 2 * r] * s, v1 = wrow[kb + 2 * r + 1] * s;
            unsigned h0 = bf16bits(v0), h1 = bf16bits(v1);
            a1.u[r] = h0 | (h1 << 16);
            if (gq < 2) {    // A2 = [W_lo | 0]: W_lo pairs with h_hi (k=0..15)
                unsigned l0 = bf16bits(v0 - fromhi(h0)), l1 = bf16bits(v1 - fromhi(h1));
                a2.u[r] = l0 | (l1 << 16);
            } else {
                a2.u[r] = 0u;
            }
        }
        A1[g] = a1.v;  A2[g] = a2.v;
        const size_t bb = (size_t)f * 64 + g * 16 + gq * 4;
        biasC[g] = f32x4{(bih[bb + 0] + bhh[bb + 0]) * s, (bih[bb + 1] + bhh[bb + 1]) * s,
                         (bih[bb + 2] + bhh[bb + 2]) * s, (bih[bb + 3] + bhh[bb + 3]) * s};
        wxs[g]   = f32x4{Wih[bb + 0] * s, Wih[bb + 1] * s, Wih[bb + 2] * s, Wih[bb + 3] * s};
    }

    f32x4 creg;
    float hq[4];
#pragma unroll
    for (int d = 0; d < 4; ++d) {
        creg[d] = init_c[f * 16 + gq * 4 + d];
        hq[d]   = init_h[f * 16 + gq * 4 + d];
    }

    unsigned* const wrHi = &sh[wv][col][2 * gq];
    const s16x8* const rdB1 = (const s16x8*)&sh[wv][col][4 * gq];

    s16x8 B1;
    // hq -> bf16 hi/lo via v_cvt_pk_bf16_f32 -> LDS -> fenced b128 read
#define REBUILD_B1()                                                            \
    {                                                                           \
        const unsigned p0 = cvtpk(hq[0], hq[1]);                                \
        const unsigned p1 = cvtpk(hq[2], hq[3]);                                \
        const float l0 = hq[0] - __uint_as_float(p0 << 16);                     \
        const float l1 = hq[1] - __uint_as_float(p0 & 0xFFFF0000u);             \
        const float l2 = hq[2] - __uint_as_float(p1 << 16);                     \
        const float l3 = hq[3] - __uint_as_float(p1 & 0xFFFF0000u);             \
        const unsigned q0 = cvtpk(l0, l1);                                      \
        const unsigned q1 = cvtpk(l2, l3);                                      \
        *(uint2*)(wrHi)     = make_uint2(p0, p1);                               \
        *(uint2*)(wrHi + 8) = make_uint2(q0, q1);                               \
        asm volatile("s_waitcnt lgkmcnt(0)" ::: "memory");                      \
        __builtin_amdgcn_sched_barrier(0);                                      \
        B1 = *rdB1;                                                             \
        asm volatile("s_waitcnt lgkmcnt(0)" ::: "memory");                      \
        __builtin_amdgcn_sched_barrier(0);                                      \
    }
    REBUILD_B1();

    const float* __restrict__ xp = xt + (size_t)f * Bsz + bglob;
    float xv = xp[0];

    for (int t = 0; t < Tn; ++t) {
        const float xnext = xp[(t + 1 < Tn) ? Fn * Bsz : 0];
        xp += Fn * Bsz;

        f32x4 acc0 = __builtin_amdgcn_mfma_f32_16x16x32_bf16(A2[0], B1, biasC[0], 0, 0, 0);
        f32x4 acc1 = __builtin_amdgcn_mfma_f32_16x16x32_bf16(A2[1], B1, biasC[1], 0, 0, 0);
        f32x4 acc2 = __builtin_amdgcn_mfma_f32_16x16x32_bf16(A2[2], B1, biasC[2], 0, 0, 0);
        f32x4 acc3 = __builtin_amdgcn_mfma_f32_16x16x32_bf16(A2[3], B1, biasC[3], 0, 0, 0);
        acc0 = __builtin_amdgcn_mfma_f32_16x16x32_bf16(A1[0], B1, acc0, 0, 0, 0);
        acc1 = __builtin_amdgcn_mfma_f32_16x16x32_bf16(A1[1], B1, acc1, 0, 0, 0);
        acc2 = __builtin_amdgcn_mfma_f32_16x16x32_bf16(A1[2], B1, acc2, 0, 0, 0);
        acc3 = __builtin_amdgcn_mfma_f32_16x16x32_bf16(A1[3], B1, acc3, 0, 0, 0);

#pragma unroll
        for (int d = 0; d < 4; ++d) {
            const float gi = __fmaf_rn(wxs[0][d], xv, acc0[d]);
            const float gf = __fmaf_rn(wxs[1][d], xv, acc1[d]);
            const float gg = fminf(__fmaf_rn(wxs[2][d], xv, acc2[d]), 100.0f);
            const float go = __fmaf_rn(wxs[3][d], xv, acc3[d]);
            const float Ei = fexp2(gi);
            const float Ef = fexp2(gf);
            const float Eg = fexp2(gg);
            const float Eo = fexp2(go);
            const float pi = 1.0f + Ei, pf = 1.0f + Ef, pg = 1.0f + Eg;
            const float pig = pi * pg;
            const float R3  = frcp(pig * pf);     // shared reciprocal
            const float Rf  = pig * R3;           // sigmoid(f)
            const float Rig = pf * R3;            // 1/((1+Ei)(1+Eg))
            const float cn  = __fmaf_rn(creg[d], Rf, (Eg - 1.0f) * Rig);
            creg[d] = cn;
            const float cs  = fminf(cn * L2E2, 80.0f);
            const float Ec  = fexp2(cs);
            const float Roc = frcp((1.0f + Eo) * (1.0f + Ec));
            hq[d] = (Ec - 1.0f) * Roc;
        }

        REBUILD_B1();
        xv = xnext;
    }

    *(f32x4*)(&hout[(size_t)bglob * (Fn * 16) + f * 16 + gq * 4]) =
        f32x4{hq[0], hq[1], hq[2], hq[3]};
}

// ---------- kernel 3: out[b] = b_fuse + sum_k hout[b][k]*W_fuse[k] ----------
__global__ __launch_bounds__(256) void fuse_out(const float* __restrict__ hout,
                                                const float* __restrict__ Wf,
                                                const float* __restrict__ bfu,
                                                float* __restrict__ out) {
    __shared__ float part[4];
    const int b = blockIdx.x, tid = threadIdx.x;
    float acc = 0.0f;
#pragma unroll
    for (int q = 0; q < 8; ++q) {
        const int k = q * 256 + tid;
        acc = __fmaf_rn(hout[(size_t)b * (Fn * 16) + k], Wf[k], acc);
    }
#pragma unroll
    for (int off = 32; off; off >>= 1) acc += __shfl_down(acc, off, 64);
    if ((tid & 63) == 0) part[tid >> 6] = acc;
    __syncthreads();
    if (tid == 0) out[b] = part[0] + part[1] + part[2] + part[3] + bfu[0];
}

extern "C" void kernel_launch(void* const* d_in, const int* in_sizes, int n_in,
                              void* d_out, int out_size, void* d_ws, size_t ws_size,
                              hipStream_t stream) {
    const float* x      = (const float*)d_in[0];
    const float* Wih    = (const float*)d_in[1];
    const float* Whh    = (const float*)d_in[2];
    const float* bih    = (const float*)d_in[3];
    const float* bhh    = (const float*)d_in[4];
    const float* init_h = (const float*)d_in[5];
    const float* init_c = (const float*)d_in[6];
    const float* Wf     = (const float*)d_in[7];
    const float* bf     = (const float*)d_in[8];
    float* out = (float*)d_out;

    char* ws = (char*)d_ws;
    float* xt   = (float*)ws;                          // 134,217,728 B  (T,F,B)
    float* hout = (float*)(ws + (size_t)134217728);    // 8,388,608 B   (B, F*16)

    transpose_x<<<dim3(32, 4, 256), dim3(32, 8), 0, stream>>>(x, xt);
    lstm_fwd<<<2048, 256, 0, stream>>>(xt, Wih, Whh, bih, bhh, init_h, init_c, hout);
    fuse_out<<<Bsz, 256, 0, stream>>>(hout, Wf, bf, out);
}

// Round 9
// 650.930 us; speedup vs baseline: 44.9060x; 1.0679x over previous
//
#include <hip/hip_runtime.h>

#define Bsz 1024
#define Tn  256
#define Fn  128

typedef float f32x4 __attribute__((ext_vector_type(4)));
typedef float v2f   __attribute__((ext_vector_type(2)));
typedef short s16x8 __attribute__((ext_vector_type(8)));

#define LOG2E 1.44269504088896f
#define L2E2  2.88539008177793f

__device__ __forceinline__ float frcp(float x)  { return __builtin_amdgcn_rcpf(x); }
__device__ __forceinline__ float fexp2(float x) { return __builtin_amdgcn_exp2f(x); }
__device__ __forceinline__ unsigned bf16bits(float v) {   // RNE f32 -> bf16 bits
    unsigned x = __float_as_uint(v);
    return (x + 0x7FFFu + ((x >> 16) & 1u)) >> 16;
}
__device__ __forceinline__ float fromhi(unsigned hb) { return __uint_as_float(hb << 16); }
__device__ __forceinline__ unsigned cvtpk(float a, float b) {  // low=bf16(a), high=bf16(b)
    unsigned r; asm("v_cvt_pk_bf16_f32 %0, %1, %2" : "=v"(r) : "v"(a), "v"(b)); return r;
}

union FragU { unsigned u[4]; s16x8 v; };

// ---------- packed 2-cell LSTM activation (exp2 domain) ----------
// 8 exp2 + 2 rcp (3-term shared) + 1 rcp (pair-shared) = 11 trans / 2 cells.
// All elementwise algebra as v2f -> v_pk_* (2 lanes of work per instr).
__device__ __forceinline__ v2f act_pair(v2f a0, v2f a1, v2f a2, v2f a3,
                                        v2f wx0, v2f wx1, v2f wx2, v2f wx3,
                                        v2f xv2, v2f& c2) {
    const v2f one = (v2f)1.0f;
    const v2f gi = __builtin_elementwise_fma(wx0, xv2, a0);
    const v2f gf = __builtin_elementwise_fma(wx1, xv2, a1);
    const v2f gg = __builtin_elementwise_min(
                       __builtin_elementwise_fma(wx2, xv2, a2), (v2f)100.0f);
    const v2f go = __builtin_elementwise_fma(wx3, xv2, a3);
    const v2f Ei = {fexp2(gi.x), fexp2(gi.y)};
    const v2f Ef = {fexp2(gf.x), fexp2(gf.y)};
    const v2f Eg = {fexp2(gg.x), fexp2(gg.y)};
    const v2f Eo = {fexp2(go.x), fexp2(go.y)};
    const v2f pi = one + Ei, pf = one + Ef, pg = one + Eg, po = one + Eo;
    const v2f pig = pi * pg;
    const v2f p3  = pig * pf;
    const v2f R3  = {frcp(p3.x), frcp(p3.y)};      // 1/((1+Ei)(1+Eg)(1+Ef))
    const v2f Rf  = pig * R3;                      // sigmoid(f)
    const v2f Rig = pf  * R3;                      // 1/((1+Ei)(1+Eg))
    const v2f cn  = __builtin_elementwise_fma(c2, Rf, (Eg - one) * Rig);
    c2 = cn;
    const v2f cs  = __builtin_elementwise_min(cn * (v2f)L2E2, (v2f)80.0f);
    const v2f Ec  = {fexp2(cs.x), fexp2(cs.y)};
    const v2f den = po * (one + Ec);
    const float R = frcp(den.x * den.y);           // pair-shared reciprocal
    const v2f Roc = {R * den.y, R * den.x};
    return (Ec - one) * Roc;                       // o * tanh(c)
}

// ---------- kernel 1: transpose x (B,T,F) -> xt (T,F,B), plain f32 ----------
__global__ __launch_bounds__(256) void transpose_x(const float* __restrict__ x,
                                                   float* __restrict__ xt) {
    __shared__ float tile[32][33];
    const int t  = blockIdx.z;
    const int bb = blockIdx.x * 32;
    const int ff = blockIdx.y * 32;
    const int tx = threadIdx.x;   // 0..31
    const int ty = threadIdx.y;   // 0..7
#pragma unroll
    for (int i = 0; i < 4; ++i) {
        int brow = ty + i * 8;
        tile[brow][tx] = x[((size_t)(bb + brow) * Tn + t) * Fn + (ff + tx)];
    }
    __syncthreads();
#pragma unroll
    for (int i = 0; i < 4; ++i) {
        int frow = ty + i * 8;
        xt[((size_t)t * Fn + (ff + frow)) * Bsz + (bb + tx)] = tile[tx][frow];
    }
}

// ---------- kernel 2: recurrent LSTM via MFMA ----------
// wave = 1 feature x 16 batches. Per gate tile g (16x16):
//   acc = MFMA(A1=[W_hi|W_hi], B1=[h_hi;h_lo], MFMA(A2=[W_lo|0], B1, biasC))
// gate = acc + wx*x on VALU (packed). h-exchange: LDS write -> memory
// clobber -> b128 broadcast read (round-4-validated; compiler emits the
// lgkmcnt before the MFMA use; same-wave LDS ops are processed in order).
__global__ __launch_bounds__(256) void lstm_fwd(const float* __restrict__ xt,    // (T,F,B)
                                                const float* __restrict__ Wih,   // (F,64)
                                                const float* __restrict__ Whh,   // (F,64,16)
                                                const float* __restrict__ bih,   // (F,64)
                                                const float* __restrict__ bhh,   // (F,64)
                                                const float* __restrict__ init_h,
                                                const float* __restrict__ init_c,
                                                float* __restrict__ hout) {      // (B, F*16)
    const int tid  = threadIdx.x;
    const int wv   = tid >> 6;
    const int lane = tid & 63;
    const int gq   = lane >> 4;          // k-octet group / D-row-group
    const int col  = lane & 15;          // A: M-row; B,D: batch col
    const int f    = blockIdx.x >> 4;
    const int bc   = ((blockIdx.x & 15) << 2) | wv;
    const int bglob = bc * 16 + col;

    __shared__ unsigned sh[4][16][20];   // stride 20 words: 16B-aligned b128 rows

    // zero-init LDS once (no uninitialized read possible)
#pragma unroll
    for (int i = tid; i < 4 * 16 * 20; i += 256) ((unsigned*)sh)[i] = 0u;
    __syncthreads();

    // ---- persistent fragments (weights pre-scaled into exp2 domain) ----
    s16x8 A1[4], A2[4];
    f32x4 biasC[4], wxs[4];
    const int kb = (gq & 1) * 8;
#pragma unroll
    for (int g = 0; g < 4; ++g) {
        const float s = (g == 2) ? L2E2 : -LOG2E;
        const float* wrow = Whh + ((size_t)f * 64 + g * 16 + col) * 16;
        FragU a1, a2;
#pragma unroll
        for (int r = 0; r < 4; ++r) {
            float v0 = wrow[kb + 2 * r] * s, v1 = wrow[kb + 2 * r + 1] * s;
            unsigned h0 = bf16bits(v0), h1 = bf16bits(v1);
            a1.u[r] = h0 | (h1 << 16);
            if (gq < 2) {    // A2 = [W_lo | 0]: W_lo pairs with h_hi (k=0..15)
                unsigned l0 = bf16bits(v0 - fromhi(h0)), l1 = bf16bits(v1 - fromhi(h1));
                a2.u[r] = l0 | (l1 << 16);
            } else {
                a2.u[r] = 0u;
            }
        }
        A1[g] = a1.v;  A2[g] = a2.v;
        const size_t bb = (size_t)f * 64 + g * 16 + gq * 4;
        biasC[g] = f32x4{(bih[bb + 0] + bhh[bb + 0]) * s, (bih[bb + 1] + bhh[bb + 1]) * s,
                         (bih[bb + 2] + bhh[bb + 2]) * s, (bih[bb + 3] + bhh[bb + 3]) * s};
        wxs[g]   = f32x4{Wih[bb + 0] * s, Wih[bb + 1] * s, Wih[bb + 2] * s, Wih[bb + 3] * s};
    }

    v2f c01, c23, h01, h23;
    {
        const int base = f * 16 + gq * 4;
        c01 = v2f{init_c[base + 0], init_c[base + 1]};
        c23 = v2f{init_c[base + 2], init_c[base + 3]};
        h01 = v2f{init_h[base + 0], init_h[base + 1]};
        h23 = v2f{init_h[base + 2], init_h[base + 3]};
    }

    unsigned* const wrHi = &sh[wv][col][2 * gq];
    const s16x8* const rdB1 = (const s16x8*)&sh[wv][col][4 * gq];

    s16x8 B1;
    // h -> bf16 hi/lo via v_cvt_pk_bf16_f32 -> LDS -> b128 broadcast read
#define REBUILD_B1()                                                            \
    {                                                                           \
        const unsigned p0 = cvtpk(h01.x, h01.y);                                \
        const unsigned p1 = cvtpk(h23.x, h23.y);                                \
        const float l0 = h01.x - __uint_as_float(p0 << 16);                     \
        const float l1 = h01.y - __uint_as_float(p0 & 0xFFFF0000u);             \
        const float l2 = h23.x - __uint_as_float(p1 << 16);                     \
        const float l3 = h23.y - __uint_as_float(p1 & 0xFFFF0000u);             \
        *(uint2*)(wrHi)     = make_uint2(p0, p1);                               \
        *(uint2*)(wrHi + 8) = make_uint2(cvtpk(l0, l1), cvtpk(l2, l3));         \
        asm volatile("" ::: "memory");                                          \
        B1 = *rdB1;                                                             \
        asm volatile("" ::: "memory");                                          \
    }
    REBUILD_B1();

    const float* __restrict__ xp = xt + (size_t)f * Bsz + bglob;
    float xv = xp[0];

    for (int t = 0; t < Tn; ++t) {
        const float xnext = xp[(t + 1 < Tn) ? Fn * Bsz : 0];
        xp += Fn * Bsz;

        f32x4 acc0 = __builtin_amdgcn_mfma_f32_16x16x32_bf16(A2[0], B1, biasC[0], 0, 0, 0);
        f32x4 acc1 = __builtin_amdgcn_mfma_f32_16x16x32_bf16(A2[1], B1, biasC[1], 0, 0, 0);
        f32x4 acc2 = __builtin_amdgcn_mfma_f32_16x16x32_bf16(A2[2], B1, biasC[2], 0, 0, 0);
        f32x4 acc3 = __builtin_amdgcn_mfma_f32_16x16x32_bf16(A2[3], B1, biasC[3], 0, 0, 0);
        acc0 = __builtin_amdgcn_mfma_f32_16x16x32_bf16(A1[0], B1, acc0, 0, 0, 0);
        acc1 = __builtin_amdgcn_mfma_f32_16x16x32_bf16(A1[1], B1, acc1, 0, 0, 0);
        acc2 = __builtin_amdgcn_mfma_f32_16x16x32_bf16(A1[2], B1, acc2, 0, 0, 0);
        acc3 = __builtin_amdgcn_mfma_f32_16x16x32_bf16(A1[3], B1, acc3, 0, 0, 0);

        const v2f xv2 = {xv, xv};
        h01 = act_pair(__builtin_shufflevector(acc0, acc0, 0, 1),
                       __builtin_shufflevector(acc1, acc1, 0, 1),
                       __builtin_shufflevector(acc2, acc2, 0, 1),
                       __builtin_shufflevector(acc3, acc3, 0, 1),
                       __builtin_shufflevector(wxs[0], wxs[0], 0, 1),
                       __builtin_shufflevector(wxs[1], wxs[1], 0, 1),
                       __builtin_shufflevector(wxs[2], wxs[2], 0, 1),
                       __builtin_shufflevector(wxs[3], wxs[3], 0, 1),
                       xv2, c01);
        h23 = act_pair(__builtin_shufflevector(acc0, acc0, 2, 3),
                       __builtin_shufflevector(acc1, acc1, 2, 3),
                       __builtin_shufflevector(acc2, acc2, 2, 3),
                       __builtin_shufflevector(acc3, acc3, 2, 3),
                       __builtin_shufflevector(wxs[0], wxs[0], 2, 3),
                       __builtin_shufflevector(wxs[1], wxs[1], 2, 3),
                       __builtin_shufflevector(wxs[2], wxs[2], 2, 3),
                       __builtin_shufflevector(wxs[3], wxs[3], 2, 3),
                       xv2, c23);

        REBUILD_B1();
        xv = xnext;
    }

    *(f32x4*)(&hout[(size_t)bglob * (Fn * 16) + f * 16 + gq * 4]) =
        f32x4{h01.x, h01.y, h23.x, h23.y};
}

// ---------- kernel 3: out[b] = b_fuse + sum_k hout[b][k]*W_fuse[k] ----------
__global__ __launch_bounds__(256) void fuse_out(const float* __restrict__ hout,
                                                const float* __restrict__ Wf,
                                                const float* __restrict__ bfu,
                                                float* __restrict__ out) {
    __shared__ float part[4];
    const int b = blockIdx.x, tid = threadIdx.x;
    float acc = 0.0f;
#pragma unroll
    for (int q = 0; q < 8; ++q) {
        const int k = q * 256 + tid;
        acc = __fmaf_rn(hout[(size_t)b * (Fn * 16) + k], Wf[k], acc);
    }
#pragma unroll
    for (int off = 32; off; off >>= 1) acc += __shfl_down(acc, off, 64);
    if ((tid & 63) == 0) part[tid >> 6] = acc;
    __syncthreads();
    if (tid == 0) out[b] = part[0] + part[1] + part[2] + part[3] + bfu[0];
}

extern "C" void kernel_launch(void* const* d_in, const int* in_sizes, int n_in,
                              void* d_out, int out_size, void* d_ws, size_t ws_size,
                              hipStream_t stream) {
    const float* x      = (const float*)d_in[0];
    const float* Wih    = (const float*)d_in[1];
    const float* Whh    = (const float*)d_in[2];
    const float* bih    = (const float*)d_in[3];
    const float* bhh    = (const float*)d_in[4];
    const float* init_h = (const float*)d_in[5];
    const float* init_c = (const float*)d_in[6];
    const float* Wf     = (const float*)d_in[7];
    const float* bf     = (const float*)d_in[8];
    float* out = (float*)d_out;

    char* ws = (char*)d_ws;
    float* xt   = (float*)ws;                          // 134,217,728 B  (T,F,B)
    float* hout = (float*)(ws + (size_t)134217728);    // 8,388,608 B   (B, F*16)

    transpose_x<<<dim3(32, 4, 256), dim3(32, 8), 0, stream>>>(x, xt);
    lstm_fwd<<<2048, 256, 0, stream>>>(xt, Wih, Whh, bih, bhh, init_h, init_c, hout);
    fuse_out<<<Bsz, 256, 0, stream>>>(hout, Wf, bf, out);
}

// Round 10
// 583.926 us; speedup vs baseline: 50.0589x; 1.1147x over previous
//
#include <hip/hip_runtime.h>

#define Bsz 1024
#define Tn  256
#define Fn  128

typedef float f32x4 __attribute__((ext_vector_type(4)));
typedef float v2f   __attribute__((ext_vector_type(2)));
typedef short s16x8 __attribute__((ext_vector_type(8)));

#define LOG2E 1.44269504088896f
#define L2E2  2.88539008177793f

__device__ __forceinline__ float frcp(float x)  { return __builtin_amdgcn_rcpf(x); }
__device__ __forceinline__ float fexp2(float x) { return __builtin_amdgcn_exp2f(x); }
__device__ __forceinline__ unsigned bf16bits(float v) {   // RNE f32 -> bf16 bits
    unsigned x = __float_as_uint(v);
    return (x + 0x7FFFu + ((x >> 16) & 1u)) >> 16;
}
__device__ __forceinline__ float fromhi(unsigned hb) { return __uint_as_float(hb << 16); }
__device__ __forceinline__ unsigned cvtpk(float a, float b) {  // low=bf16(a), high=bf16(b)
    unsigned r; asm("v_cvt_pk_bf16_f32 %0, %1, %2" : "=v"(r) : "v"(a), "v"(b)); return r;
}

union FragU { unsigned u[4]; s16x8 v; };

// ---------- packed 2-cell LSTM activation (exp2 domain) ----------
__device__ __forceinline__ v2f act_pair(v2f gi, v2f gf, v2f a2, v2f go, v2f& c2) {
    const v2f one = (v2f)1.0f;
    const v2f gg = __builtin_elementwise_min(a2, (v2f)100.0f);   // kills 0*inf
    const v2f Ei = {fexp2(gi.x), fexp2(gi.y)};
    const v2f Ef = {fexp2(gf.x), fexp2(gf.y)};
    const v2f Eg = {fexp2(gg.x), fexp2(gg.y)};
    const v2f Eo = {fexp2(go.x), fexp2(go.y)};
    const v2f pi = one + Ei, pf = one + Ef, pg = one + Eg, po = one + Eo;
    const v2f pig = pi * pg;
    const v2f p3  = pig * pf;
    const v2f R3  = {frcp(p3.x), frcp(p3.y)};
    const v2f Rf  = pig * R3;                      // sigmoid(f)
    const v2f Rig = pf  * R3;                      // 1/((1+Ei)(1+Eg))
    const v2f cn  = __builtin_elementwise_fma(c2, Rf, (Eg - one) * Rig);
    c2 = cn;
    const v2f cs  = __builtin_elementwise_min(cn * (v2f)L2E2, (v2f)80.0f);
    const v2f Ec  = {fexp2(cs.x), fexp2(cs.y)};
    const v2f den = po * (one + Ec);
    const float R = frcp(den.x * den.y);           // pair-shared reciprocal
    const v2f Roc = {R * den.y, R * den.x};
    return (Ec - one) * Roc;                       // o * tanh(c)
}

// ---------- kernel 1: transpose x (B,T,F) f32 -> (T,F,B) packed (lo16<<16 | hi16) ----------
__global__ __launch_bounds__(256) void transpose_pack(const float* __restrict__ x,
                                                      unsigned* __restrict__ xt) {
    __shared__ float tile[32][33];
    const int t  = blockIdx.z;
    const int bb = blockIdx.x * 32;
    const int ff = blockIdx.y * 32;
    const int tx = threadIdx.x;   // 0..31
    const int ty = threadIdx.y;   // 0..7
#pragma unroll
    for (int i = 0; i < 4; ++i) {
        int brow = ty + i * 8;
        tile[brow][tx] = x[((size_t)(bb + brow) * Tn + t) * Fn + (ff + tx)];
    }
    __syncthreads();
#pragma unroll
    for (int i = 0; i < 4; ++i) {
        int frow = ty + i * 8;
        float v = tile[tx][frow];
        unsigned hb = bf16bits(v);
        unsigned lb = bf16bits(v - fromhi(hb));
        // low half = x_hi, high half = x_lo: directly usable as B2 word
        xt[((size_t)t * Fn + (ff + frow)) * Bsz + (bb + tx)] = hb | (lb << 16);
    }
}

// ---------- kernel 2: recurrent LSTM via MFMA, ZERO LDS ----------
// wave = 1 feature x 16 batches. Believed k-map: slot(gq,r) -> h-index
// 4*gq+(r&3); r<4 pairs hi, r>=4 pairs lo. With this map, lane(col,gq)'s
// B-fragment = the 4 h-values that SAME lane owns from the D-output
// (rows 4gq..4gq+3 of batch col) -> B1 built in registers, no exchange.
//   acc = MFMA(A1=[W_hi|W_hi], B1=[h_hi;h_lo],
//         MFMA(A2=[W_lo|wx],   B2=[h_hi;x_hi,x_lo], biasC))
// A/B share the map => any common layout mismatch cancels exactly
// (framework validated by rounds 7-9, absmax 3.8e-6).
__global__ __launch_bounds__(256, 4) void lstm_fwd(const unsigned* __restrict__ xt,  // (T,F,B) packed
                                                   const float* __restrict__ Wih,    // (F,64)
                                                   const float* __restrict__ Whh,    // (F,64,16)
                                                   const float* __restrict__ bih,    // (F,64)
                                                   const float* __restrict__ bhh,    // (F,64)
                                                   const float* __restrict__ init_h,
                                                   const float* __restrict__ init_c,
                                                   float* __restrict__ hout) {       // (B, F*16)
    const int tid  = threadIdx.x;
    const int wv   = tid >> 6;
    const int lane = tid & 63;
    const int gq   = lane >> 4;          // k-quad group / D-row-group
    const int col  = lane & 15;          // A: M-row; B,D: batch col
    const int f    = blockIdx.x >> 4;
    const int bc   = ((blockIdx.x & 15) << 2) | wv;
    const int bglob = bc * 16 + col;

    // ---- persistent fragments (weights pre-scaled into exp2 domain) ----
    s16x8 A1[4], A2[4];
    f32x4 biasC[4];
#pragma unroll
    for (int g = 0; g < 4; ++g) {
        const float s = (g == 2) ? L2E2 : -LOG2E;
        const float* wrow = Whh + ((size_t)f * 64 + g * 16 + col) * 16;
        // this lane's k-quad: h indices 4*gq .. 4*gq+3
        float v0 = wrow[4 * gq + 0] * s, v1 = wrow[4 * gq + 1] * s;
        float v2 = wrow[4 * gq + 2] * s, v3 = wrow[4 * gq + 3] * s;
        unsigned h0 = bf16bits(v0), h1 = bf16bits(v1);
        unsigned h2 = bf16bits(v2), h3 = bf16bits(v3);
        FragU a1, a2;
        a1.u[0] = h0 | (h1 << 16);
        a1.u[1] = h2 | (h3 << 16);
        a1.u[2] = a1.u[0];               // W_hi pairs h_lo too
        a1.u[3] = a1.u[1];
        a2.u[0] = bf16bits(v0 - fromhi(h0)) | (bf16bits(v1 - fromhi(h1)) << 16);
        a2.u[1] = bf16bits(v2 - fromhi(h2)) | (bf16bits(v3 - fromhi(h3)) << 16);
        // x-slots (pair with B2 word2 = {x_hi, x_lo}):
        const float wx = Wih[(size_t)f * 64 + g * 16 + col] * s;
        const unsigned wxh = bf16bits(wx);
        const unsigned wxl = bf16bits(wx - fromhi(wxh));
        a2.u[2] = (gq == 0) ? (wxh | (wxh << 16))      // wx_hi*x_hi + wx_hi*x_lo
                : (gq == 1) ? wxl : 0u;                // wx_lo*x_hi
        a2.u[3] = 0u;
        A1[g] = a1.v;  A2[g] = a2.v;
        const size_t bb = (size_t)f * 64 + g * 16 + gq * 4;
        biasC[g] = f32x4{(bih[bb + 0] + bhh[bb + 0]) * s, (bih[bb + 1] + bhh[bb + 1]) * s,
                         (bih[bb + 2] + bhh[bb + 2]) * s, (bih[bb + 3] + bhh[bb + 3]) * s};
    }

    v2f c01, c23, h01, h23;
    {
        const int base = f * 16 + gq * 4;
        c01 = v2f{init_c[base + 0], init_c[base + 1]};
        c23 = v2f{init_c[base + 2], init_c[base + 3]};
        h01 = v2f{init_h[base + 0], init_h[base + 1]};
        h23 = v2f{init_h[base + 2], init_h[base + 3]};
    }

    unsigned p0, p1, q0, q1;   // B1 words: hi pairs, lo pairs (all in registers)
#define REBUILD_B1()                                                            \
    {                                                                           \
        p0 = cvtpk(h01.x, h01.y);                                               \
        p1 = cvtpk(h23.x, h23.y);                                               \
        const float l0 = h01.x - __uint_as_float(p0 << 16);                     \
        const float l1 = h01.y - __uint_as_float(p0 & 0xFFFF0000u);             \
        const float l2 = h23.x - __uint_as_float(p1 << 16);                     \
        const float l3 = h23.y - __uint_as_float(p1 & 0xFFFF0000u);             \
        q0 = cvtpk(l0, l1);                                                     \
        q1 = cvtpk(l2, l3);                                                     \
    }
    REBUILD_B1();

    const unsigned* __restrict__ xp = xt + (size_t)f * Bsz + bglob;
    unsigned xw = xp[0];

    for (int t = 0; t < Tn; ++t) {
        const unsigned xnext = xp[(t + 1 < Tn) ? Fn * Bsz : 0];
        xp += Fn * Bsz;

        FragU b1, b2;
        b1.u[0] = p0; b1.u[1] = p1; b1.u[2] = q0; b1.u[3] = q1;
        b2.u[0] = p0; b2.u[1] = p1; b2.u[2] = xw; b2.u[3] = 0u;

        f32x4 acc0 = __builtin_amdgcn_mfma_f32_16x16x32_bf16(A2[0], b2.v, biasC[0], 0, 0, 0);
        f32x4 acc1 = __builtin_amdgcn_mfma_f32_16x16x32_bf16(A2[1], b2.v, biasC[1], 0, 0, 0);
        f32x4 acc2 = __builtin_amdgcn_mfma_f32_16x16x32_bf16(A2[2], b2.v, biasC[2], 0, 0, 0);
        f32x4 acc3 = __builtin_amdgcn_mfma_f32_16x16x32_bf16(A2[3], b2.v, biasC[3], 0, 0, 0);
        acc0 = __builtin_amdgcn_mfma_f32_16x16x32_bf16(A1[0], b1.v, acc0, 0, 0, 0);
        acc1 = __builtin_amdgcn_mfma_f32_16x16x32_bf16(A1[1], b1.v, acc1, 0, 0, 0);
        acc2 = __builtin_amdgcn_mfma_f32_16x16x32_bf16(A1[2], b1.v, acc2, 0, 0, 0);
        acc3 = __builtin_amdgcn_mfma_f32_16x16x32_bf16(A1[3], b1.v, acc3, 0, 0, 0);

        h01 = act_pair(__builtin_shufflevector(acc0, acc0, 0, 1),
                       __builtin_shufflevector(acc1, acc1, 0, 1),
                       __builtin_shufflevector(acc2, acc2, 0, 1),
                       __builtin_shufflevector(acc3, acc3, 0, 1), c01);
        h23 = act_pair(__builtin_shufflevector(acc0, acc0, 2, 3),
                       __builtin_shufflevector(acc1, acc1, 2, 3),
                       __builtin_shufflevector(acc2, acc2, 2, 3),
                       __builtin_shufflevector(acc3, acc3, 2, 3), c23);

        REBUILD_B1();
        xw = xnext;
    }

    *(f32x4*)(&hout[(size_t)bglob * (Fn * 16) + f * 16 + gq * 4]) =
        f32x4{h01.x, h01.y, h23.x, h23.y};
}

// ---------- kernel 3: out[b] = b_fuse + sum_k hout[b][k]*W_fuse[k] ----------
__global__ __launch_bounds__(256) void fuse_out(const float* __restrict__ hout,
                                                const float* __restrict__ Wf,
                                                const float* __restrict__ bfu,
                                                float* __restrict__ out) {
    __shared__ float part[4];
    const int b = blockIdx.x, tid = threadIdx.x;
    float acc = 0.0f;
#pragma unroll
    for (int q = 0; q < 8; ++q) {
        const int k = q * 256 + tid;
        acc = __fmaf_rn(hout[(size_t)b * (Fn * 16) + k], Wf[k], acc);
    }
#pragma unroll
    for (int off = 32; off; off >>= 1) acc += __shfl_down(acc, off, 64);
    if ((tid & 63) == 0) part[tid >> 6] = acc;
    __syncthreads();
    if (tid == 0) out[b] = part[0] + part[1] + part[2] + part[3] + bfu[0];
}

extern "C" void kernel_launch(void* const* d_in, const int* in_sizes, int n_in,
                              void* d_out, int out_size, void* d_ws, size_t ws_size,
                              hipStream_t stream) {
    const float* x      = (const float*)d_in[0];
    const float* Wih    = (const float*)d_in[1];
    const float* Whh    = (const float*)d_in[2];
    const float* bih    = (const float*)d_in[3];
    const float* bhh    = (const float*)d_in[4];
    const float* init_h = (const float*)d_in[5];
    const float* init_c = (const float*)d_in[6];
    const float* Wf     = (const float*)d_in[7];
    const float* bf     = (const float*)d_in[8];
    float* out = (float*)d_out;

    char* ws = (char*)d_ws;
    unsigned* xtp = (unsigned*)ws;                      // (T,F,B) u32 = 134,217,728 B
    float* hout   = (float*)(ws + (size_t)134217728);   // (B, F*16) = 8,388,608 B

    transpose_pack<<<dim3(32, 4, 256), dim3(32, 8), 0, stream>>>(x, xtp);
    lstm_fwd<<<2048, 256, 0, stream>>>(xtp, Wih, Whh, bih, bhh, init_h, init_c, hout);
    fuse_out<<<Bsz, 256, 0, stream>>>(hout, Wf, bf, out);
}